// Round 18
// baseline (672.200 us; speedup 1.0000x reference)
//
#include <hip/hip_runtime.h>
#include <hip/hip_bf16.h>
#include <math.h>

typedef __attribute__((ext_vector_type(8))) short short8;
typedef __attribute__((ext_vector_type(4))) float f32x4;

#define NTOK 2048
#define HID  2880
#define QKVD 5120
#define KOFF 4096
#define VOFF 4608
#define ATTD 4096   // N_HEADS*HEAD_DIM

__device__ __forceinline__ unsigned short f2bf(float f) {
  union { float f; unsigned int u; } v; v.f = f;
  unsigned int u = v.u;
  unsigned int r = (u + 0x7FFFu + ((u >> 16) & 1u)) >> 16;
  return (unsigned short)r;
}
__device__ __forceinline__ float bf2f(unsigned short h) {
  union { unsigned int u; float f; } v; v.u = ((unsigned int)h) << 16; return v.f;
}
__device__ __forceinline__ void gload_lds16(const unsigned short* g, unsigned short* l) {
  __builtin_amdgcn_global_load_lds(
      (const __attribute__((address_space(1))) unsigned int*)g,
      (__attribute__((address_space(3))) unsigned int*)l, 16, 0, 0);
}
#define MFMA16(a, b, c) __builtin_amdgcn_mfma_f32_16x16x32_bf16((a), (b), (c), 0, 0, 0)

// ---------------- prep: rmsnorm || w_qkv cvt || w_out cvt || rope table ----------
__global__ __launch_bounds__(256) void prep_kernel(
    const float* __restrict__ x, const float* __restrict__ scale,
    unsigned short* __restrict__ t,
    const float* __restrict__ w1, unsigned short* __restrict__ w1bf,
    const float* __restrict__ w2, unsigned short* __restrict__ w2bf,
    float* __restrict__ ctab, float* __restrict__ stab) {
  __shared__ float red[4];
  const int bid = blockIdx.x;
  const int tid = threadIdx.x;
  if (bid < 2048) {
    const float4* xr = (const float4*)(x + (size_t)bid * HID);
    const float4* sc = (const float4*)scale;
    float ss = 0.f;
    for (int c = tid; c < HID / 4; c += 256) {
      float4 v = xr[c];
      ss += v.x * v.x + v.y * v.y + v.z * v.z + v.w * v.w;
    }
    #pragma unroll
    for (int m = 1; m < 64; m <<= 1) ss += __shfl_xor(ss, m);
    if ((tid & 63) == 0) red[tid >> 6] = ss;
    __syncthreads();
    float tot = red[0] + red[1] + red[2] + red[3];
    float rs = rsqrtf(tot / (float)HID + 1e-5f);
    for (int c = tid; c < HID / 4; c += 256) {
      float4 v = xr[c];
      float4 s4 = sc[c];
      ushort4 o;
      o.x = f2bf(v.x * rs * s4.x); o.y = f2bf(v.y * rs * s4.y);
      o.z = f2bf(v.z * rs * s4.z); o.w = f2bf(v.w * rs * s4.w);
      *(ushort4*)&t[(size_t)bid * HID + c * 4] = o;
    }
  } else if (bid < 8528) {
    const float* src; unsigned short* dst; long base0;
    if (bid < 5648) { src = w1; dst = w1bf; base0 = (long)(bid - 2048) * 1024; }
    else            { src = w2; dst = w2bf; base0 = (long)(bid - 5648) * 1024; }
    #pragma unroll
    for (int k2 = 0; k2 < 4; ++k2) {
      long base = (base0 + k2 * 256 + tid) * 4;
      float4 v = *(const float4*)&src[base];
      ushort4 o;
      o.x = f2bf(v.x); o.y = f2bf(v.y); o.z = f2bf(v.z); o.w = f2bf(v.w);
      *(ushort4*)&dst[base] = o;
    }
  } else {
    int idx = (bid - 8528) * 256 + tid;     // < 65536
    int pos = idx >> 5, i = idx & 31;
    const double theta = 150000.0;
    const double two_pi = 6.283185307179586476925286766559;
    double freq = pow(theta, (double)i / 32.0);
    double interp = 1.0 / (32.0 * freq);
    double extrap = 1.0 / freq;
    double low  = 32.0 * log(4096.0 / (32.0 * two_pi)) / log(theta);
    double high = 32.0 * log(4096.0 / (1.0  * two_pi)) / log(theta);
    double ramp = ((double)i - low) / (high - low);
    ramp = ramp < 0.0 ? 0.0 : (ramp > 1.0 ? 1.0 : ramp);
    double maskv = 1.0 - ramp;
    double inv = interp * (1.0 - maskv) + extrap * maskv;
    double ang = (double)pos * inv;
    double conc = 0.1 * log(32.0) + 1.0;
    ctab[idx] = (float)(cos(ang) * conc);
    stab[idx] = (float)(sin(ang) * conc);
  }
}

// ---------------- Pipelined GEMM, single-buffer LDS, 4-5 blocks/CU ----------
// C[M,NC] = A[M,K]bf16 @ B[NC,K]bf16^T (+bias, +resid)
// BM=128, BN in {160,96}; BK=64; 256 thr = 4 waves (2M x 2N); SINGLE LDS buf
// (36/28 KB) -> 4-5 blocks/CU. Per tile: barrier(reads done) -> stage(t) ->
// vmcnt(0) -> barrier -> ds_read+MFMA. Staging exposed within a block;
// hidden by de-phased co-resident blocks (m97/m114 mechanism).
template<int BN, bool RESID, int MINB>
__global__ __launch_bounds__(256, MINB) void gemm_kernel(
    const unsigned short* __restrict__ A, const unsigned short* __restrict__ B,
    const float* __restrict__ bias, const float* __restrict__ resid,
    void* __restrict__ Cout, int K, int NC) {
  constexpr int NF = BN / 32;
  __shared__ unsigned short sA[8192];
  __shared__ unsigned short sB[BN * 64];

  const int tid = threadIdx.x;
  const int q8 = gridDim.x >> 3;
  const int sw = ((int)blockIdx.x & 7) * q8 + ((int)blockIdx.x >> 3);
  const int m0 = (sw & 15) * 128;
  const int n0 = (sw >> 4) * BN;

  const int lane = tid & 63, wid = tid >> 6;
  const int fr = lane & 15, fq = lane >> 4;
  const int wr = wid >> 1, wc = wid & 1;
  const int swz = (fr & 7) << 4;
  const int r_st = tid >> 3;
  const int c8_st = ((tid & 7) ^ ((tid >> 3) & 7)) * 8;
  const int wlds = wid << 9;

  const unsigned short* Ag = A + (size_t)(m0 + r_st) * K + c8_st;
  const unsigned short* Bg = B + (size_t)(n0 + r_st) * K + c8_st;

  f32x4 acc[4][NF] = {};
  const int NT = K >> 6;

  auto LDA_ = [&](int mf, int ks) -> short8 {
    int row = wr * 64 + mf * 16 + fr;
    int cb = (ks * 64 + fq * 16) ^ swz;
    return *(const short8*)((const char*)&sA[0] + row * 128 + cb);
  };
  auto LDB_ = [&](int nf, int ks) -> short8 {
    int row = wc * (NF * 16) + nf * 16 + fr;
    int cb = (ks * 64 + fq * 16) ^ swz;
    return *(const short8*)((const char*)&sB[0] + row * 128 + cb);
  };
  auto issue_tile = [&](int tt) {
    const unsigned short* Agt = Ag + (size_t)tt * 64;
    const unsigned short* Bgt = Bg + (size_t)tt * 64;
    #pragma unroll
    for (int s = 0; s < 4; ++s)
      gload_lds16(Agt + (size_t)(s * 32) * K, &sA[s * 2048 + wlds]);
    #pragma unroll
    for (int s = 0; s < NF; ++s)
      gload_lds16(Bgt + (size_t)(s * 32) * K, &sB[s * 2048 + wlds]);
  };

  for (int t = 0; t < NT; ++t) {
    // all waves' reads of the buffer (tile t-1) are complete
    asm volatile("s_barrier" ::: "memory");
    issue_tile(t);
    asm volatile("s_waitcnt vmcnt(0)" ::: "memory");
    asm volatile("s_barrier" ::: "memory");
    __builtin_amdgcn_sched_barrier(0);
    short8 afr0[4], bfr0[NF], afr1[4], bfr1[NF];
    #pragma unroll
    for (int mf = 0; mf < 4; ++mf) afr0[mf] = LDA_(mf, 0);
    #pragma unroll
    for (int nf = 0; nf < NF; ++nf) bfr0[nf] = LDB_(nf, 0);
    #pragma unroll
    for (int mf = 0; mf < 4; ++mf) afr1[mf] = LDA_(mf, 1);
    #pragma unroll
    for (int nf = 0; nf < NF; ++nf) bfr1[nf] = LDB_(nf, 1);
    __builtin_amdgcn_s_setprio(1);
    #pragma unroll
    for (int mf = 0; mf < 4; ++mf)
      #pragma unroll
      for (int nf = 0; nf < NF; ++nf)
        acc[mf][nf] = MFMA16(afr0[mf], bfr0[nf], acc[mf][nf]);
    #pragma unroll
    for (int mf = 0; mf < 4; ++mf)
      #pragma unroll
      for (int nf = 0; nf < NF; ++nf)
        acc[mf][nf] = MFMA16(afr1[mf], bfr1[nf], acc[mf][nf]);
    __builtin_amdgcn_s_setprio(0);
  }

  if (!RESID) {
    unsigned short* C = (unsigned short*)Cout;
    #pragma unroll
    for (int mf = 0; mf < 4; ++mf)
      #pragma unroll
      for (int nf = 0; nf < NF; ++nf)
        #pragma unroll
        for (int r = 0; r < 4; ++r) {
          int row = m0 + wr * 64 + mf * 16 + fq * 4 + r;
          int col = n0 + wc * (NF * 16) + nf * 16 + fr;
          C[(size_t)row * NC + col] = f2bf(acc[mf][nf][r] + bias[col]);
        }
  } else {
    float* C = (float*)Cout;
    #pragma unroll
    for (int mf = 0; mf < 4; ++mf)
      #pragma unroll
      for (int nf = 0; nf < NF; ++nf)
        #pragma unroll
        for (int r = 0; r < 4; ++r) {
          int row = m0 + wr * 64 + mf * 16 + fq * 4 + r;
          int col = n0 + wc * (NF * 16) + nf * 16 + fr;
          C[(size_t)row * NC + col] = acc[mf][nf][r] + bias[col] + resid[(size_t)row * NC + col];
        }
  }
}

// ---------------- GQA attention: K/V staged ONCE per kv-head ----------------
__global__ __launch_bounds__(512) void attn_kernel(
    const unsigned short* __restrict__ qkv, const float* __restrict__ sinks,
    const float* __restrict__ ctab, const float* __restrict__ stab,
    unsigned short* __restrict__ attn) {
  const int tile = blockIdx.x;
  const int h = blockIdx.y;              // kv-head
  const int q0 = tile * 64;
  const int kbase = q0 - 127;

  __shared__ unsigned short Qsh[64][72];
  __shared__ unsigned short Ksh[192][72];
  __shared__ unsigned short Vt[64][200];   // transposed V: [dim][key]
  __shared__ unsigned short Wsh[64][200];  // P (separate: K lives all 8 iters)
  __shared__ float rowpart[4][64];
  __shared__ float invsum[64];

  const int tid = threadIdx.x;

  // ---- stage K with RoPE (192 rows x 4 chunk-pairs = 768 units)
  #pragma unroll
  for (int it = 0; it < 2; ++it) {
    int lin = tid + it * 512;
    if (lin < 768) {
      int r = lin >> 2, cp = lin & 3;
      int j = kbase + r;
      short8 oa = {}, ob = {};
      if (j >= 0 && j < NTOK) {
        const unsigned short* kp = &qkv[(size_t)j * QKVD + KOFF + h * 64 + cp * 8];
        short8 xa = *(const short8*)kp;
        short8 xb = *(const short8*)(kp + 32);
        #pragma unroll
        for (int e = 0; e < 8; ++e) {
          float c = ctab[j * 32 + cp * 8 + e], s = stab[j * 32 + cp * 8 + e];
          float x1 = bf2f((unsigned short)xa[e]), x2 = bf2f((unsigned short)xb[e]);
          oa[e] = (short)f2bf(x1 * c - x2 * s);
          ob[e] = (short)f2bf(x2 * c + x1 * s);
        }
      }
      *(short8*)&Ksh[r][cp * 8] = oa;
      *(short8*)&Ksh[r][cp * 8 + 32] = ob;
    }
  }
  // ---- stage V transposed: coalesced column loads, conflict-free b128 writes
  {
    const int d = tid & 63;
    const int jg0 = tid >> 6;              // 0..7
    const unsigned short* vcol = qkv + VOFF + (size_t)h * 64 + d;
    #pragma unroll
    for (int it = 0; it < 3; ++it) {
      int jg = jg0 + it * 8;               // 0..23
      int jb = kbase + jg * 8;
      unsigned int e01 = 0, e23 = 0, e45 = 0, e67 = 0;
      if (jb >= 0) {
        e01 = (unsigned int)vcol[(size_t)(jb + 0) * QKVD]
            | ((unsigned int)vcol[(size_t)(jb + 1) * QKVD] << 16);
        e23 = (unsigned int)vcol[(size_t)(jb + 2) * QKVD]
            | ((unsigned int)vcol[(size_t)(jb + 3) * QKVD] << 16);
        e45 = (unsigned int)vcol[(size_t)(jb + 4) * QKVD]
            | ((unsigned int)vcol[(size_t)(jb + 5) * QKVD] << 16);
        e67 = (unsigned int)vcol[(size_t)(jb + 6) * QKVD]
            | ((unsigned int)vcol[(size_t)(jb + 7) * QKVD] << 16);
      } else if (jb + 7 >= 0) {
        unsigned short ev[8];
        #pragma unroll
        for (int e = 0; e < 8; ++e)
          ev[e] = (jb + e >= 0) ? vcol[(size_t)(jb + e) * QKVD] : (unsigned short)0;
        e01 = ev[0] | ((unsigned int)ev[1] << 16);
        e23 = ev[2] | ((unsigned int)ev[3] << 16);
        e45 = ev[4] | ((unsigned int)ev[5] << 16);
        e67 = ev[6] | ((unsigned int)ev[7] << 16);
      }
      *(uint4*)&Vt[d][jg * 8] = make_uint4(e01, e23, e45, e67);
    }
  }

  const int lane = tid & 63;
  const int wid = tid >> 6;                // 0..7
  const int fr = lane & 15;
  const int fq = lane >> 4;
  const int fc = fq * 8;
  const int rg = wid >> 2;                 // row group (0..1)
  const int cg = wid & 3;                  // key/col group (0..3)
  const int wk0 = cg * 48;

  for (int qm = 0; qm < 8; ++qm) {
    const int gh = h * 8 + qm;
    if (tid < 256) {
      int r = tid >> 2, cp = tid & 3;
      int i = q0 + r;
      const unsigned short* qp = &qkv[(size_t)i * QKVD + gh * 64 + cp * 8];
      short8 xa = *(const short8*)qp;
      short8 xb = *(const short8*)(qp + 32);
      short8 oa, ob;
      #pragma unroll
      for (int e = 0; e < 8; ++e) {
        float c = ctab[i * 32 + cp * 8 + e], s = stab[i * 32 + cp * 8 + e];
        float x1 = bf2f((unsigned short)xa[e]), x2 = bf2f((unsigned short)xb[e]);
        oa[e] = (short)f2bf(x1 * c - x2 * s);
        ob[e] = (short)f2bf(x2 * c + x1 * s);
      }
      *(short8*)&Qsh[r][cp * 8] = oa;
      *(short8*)&Qsh[r][cp * 8 + 32] = ob;
    }
    __syncthreads();   // Q (and, iter 0, K/V) staged

    f32x4 sc[2][3] = {};
    #pragma unroll
    for (int k0 = 0; k0 < 64; k0 += 32) {
      short8 qa[2], kb[3];
      #pragma unroll
      for (int mi = 0; mi < 2; ++mi)
        qa[mi] = *(const short8*)&Qsh[rg * 32 + mi * 16 + fr][k0 + fc];
      #pragma unroll
      for (int ni = 0; ni < 3; ++ni)
        kb[ni] = *(const short8*)&Ksh[wk0 + ni * 16 + fr][k0 + fc];
      #pragma unroll
      for (int mi = 0; mi < 2; ++mi)
        #pragma unroll
        for (int ni = 0; ni < 3; ++ni)
          sc[mi][ni] = MFMA16(qa[mi], kb[ni], sc[mi][ni]);
    }

    #pragma unroll
    for (int mi = 0; mi < 2; ++mi)
      #pragma unroll
      for (int r = 0; r < 4; ++r) {
        int row = rg * 32 + mi * 16 + fq * 4 + r;
        int i = q0 + row;
        float rs = 0.f;
        #pragma unroll
        for (int ni = 0; ni < 3; ++ni) {
          int kk = wk0 + ni * 16 + fr;
          int j = kbase + kk;
          bool valid = (j >= 0) && (j <= i) && (j > i - 128);
          float pw = valid ? __expf(sc[mi][ni][r] * 0.125f) : 0.f;
          sc[mi][ni][r] = pw;
          rs += pw;
        }
        rs += __shfl_xor(rs, 1);
        rs += __shfl_xor(rs, 2);
        rs += __shfl_xor(rs, 4);
        rs += __shfl_xor(rs, 8);
        #pragma unroll
        for (int ni = 0; ni < 3; ++ni)
          Wsh[row][wk0 + ni * 16 + fr] = f2bf(sc[mi][ni][r]);
        if (fr == 0) rowpart[cg][row] = rs;
      }
    __syncthreads();   // P + partials visible

    if (tid < 64) {
      float tot = rowpart[0][tid] + rowpart[1][tid] + rowpart[2][tid] + rowpart[3][tid];
      invsum[tid] = 1.f / (tot + __expf(sinks[gh]));
    }

    f32x4 pv[2] = {};
    #pragma unroll
    for (int k0 = 0; k0 < 192; k0 += 32) {
      short8 pa[2];
      #pragma unroll
      for (int mi = 0; mi < 2; ++mi)
        pa[mi] = *(const short8*)&Wsh[rg * 32 + mi * 16 + fr][k0 + fc];
      short8 vb = *(const short8*)&Vt[cg * 16 + fr][k0 + fc];
      #pragma unroll
      for (int mi = 0; mi < 2; ++mi)
        pv[mi] = MFMA16(pa[mi], vb, pv[mi]);
    }
    __syncthreads();   // invsum visible; Wsh reads complete

    #pragma unroll
    for (int mi = 0; mi < 2; ++mi)
      #pragma unroll
      for (int r = 0; r < 4; ++r) {
        int row = rg * 32 + mi * 16 + fq * 4 + r;
        float inv = invsum[row];
        int col = cg * 16 + fr;
        attn[(size_t)(q0 + row) * ATTD + gh * 64 + col] = f2bf(pv[mi][r] * inv);
      }
  }
}

extern "C" void kernel_launch(void* const* d_in, const int* in_sizes, int n_in,
                              void* d_out, int out_size, void* d_ws, size_t ws_size,
                              hipStream_t stream) {
  const float* x          = (const float*)d_in[0];
  const float* norm_scale = (const float*)d_in[1];
  const float* sinks      = (const float*)d_in[2];
  const float* w_qkv      = (const float*)d_in[3];
  const float* b_qkv      = (const float*)d_in[4];
  const float* w_out      = (const float*)d_in[5];
  const float* b_out      = (const float*)d_in[6];
  float* out = (float*)d_out;

  char* ws = (char*)d_ws;
  unsigned short* qkv_bf = (unsigned short*)(ws);
  unsigned short* t_bf   = (unsigned short*)(ws + 20971520);
  unsigned short* attn_b = (unsigned short*)(ws + 20971520);
  unsigned short* w1bf   = (unsigned short*)(ws + 20971520 + 16777216);
  unsigned short* w2bf   = (unsigned short*)(ws + 20971520 + 16777216 + 29491200);
  float* ctab = (float*)(ws + 20971520 + 16777216 + 29491200 + 23592960);
  float* stab = ctab + NTOK * 32;

  // prep: rmsnorm (2048) || w_qkv cvt (3600) || w_out cvt (2880) || rope (256)
  prep_kernel<<<dim3(8784), dim3(256), 0, stream>>>(
      x, norm_scale, t_bf, w_qkv, w1bf, w_out, w2bf, ctab, stab);
  // GEMM1: 2048x5120x2880, tiles 128x160 -> 512 blocks (4/CU, single-buf)
  gemm_kernel<160, false, 4><<<dim3(512), dim3(256), 0, stream>>>(
      t_bf, w1bf, b_qkv, nullptr, (void*)qkv_bf, HID, QKVD);
  // attention: (32 tiles, 8 kv-heads), K/V staged once per block
  attn_kernel<<<dim3(32, 8), dim3(512), 0, stream>>>(qkv_bf, sinks, ctab, stab, attn_b);
  // GEMM2: 2048x2880x4096, tiles 128x96 -> 480 blocks (5/CU, single-buf)
  gemm_kernel<96, true, 5><<<dim3(480), dim3(256), 0, stream>>>(
      attn_b, w2bf, b_out, x, (void*)out, ATTD, HID);
}

// Round 19
// 186.871 us; speedup vs baseline: 3.5971x; 3.5971x over previous
//
#include <hip/hip_runtime.h>
#include <hip/hip_bf16.h>
#include <math.h>

typedef __attribute__((ext_vector_type(8))) short short8;
typedef __attribute__((ext_vector_type(4))) float f32x4;

#define NTOK 2048
#define HID  2880
#define QKVD 5120
#define KOFF 4096
#define VOFF 4608
#define ATTD 4096   // N_HEADS*HEAD_DIM

__device__ __forceinline__ unsigned short f2bf(float f) {
  union { float f; unsigned int u; } v; v.f = f;
  unsigned int u = v.u;
  unsigned int r = (u + 0x7FFFu + ((u >> 16) & 1u)) >> 16;
  return (unsigned short)r;
}
__device__ __forceinline__ float bf2f(unsigned short h) {
  union { unsigned int u; float f; } v; v.u = ((unsigned int)h) << 16; return v.f;
}
__device__ __forceinline__ void gload_lds16(const unsigned short* g, unsigned short* l) {
  __builtin_amdgcn_global_load_lds(
      (const __attribute__((address_space(1))) unsigned int*)g,
      (__attribute__((address_space(3))) unsigned int*)l, 16, 0, 0);
}
#define MFMA16(a, b, c) __builtin_amdgcn_mfma_f32_16x16x32_bf16((a), (b), (c), 0, 0, 0)

// ---------------- prep: rmsnorm || w_qkv cvt || w_out cvt || rope table ----------
__global__ __launch_bounds__(256) void prep_kernel(
    const float* __restrict__ x, const float* __restrict__ scale,
    unsigned short* __restrict__ t,
    const float* __restrict__ w1, unsigned short* __restrict__ w1bf,
    const float* __restrict__ w2, unsigned short* __restrict__ w2bf,
    float* __restrict__ ctab, float* __restrict__ stab) {
  __shared__ float red[4];
  const int bid = blockIdx.x;
  const int tid = threadIdx.x;
  if (bid < 2048) {
    const float4* xr = (const float4*)(x + (size_t)bid * HID);
    const float4* sc = (const float4*)scale;
    float ss = 0.f;
    for (int c = tid; c < HID / 4; c += 256) {
      float4 v = xr[c];
      ss += v.x * v.x + v.y * v.y + v.z * v.z + v.w * v.w;
    }
    #pragma unroll
    for (int m = 1; m < 64; m <<= 1) ss += __shfl_xor(ss, m);
    if ((tid & 63) == 0) red[tid >> 6] = ss;
    __syncthreads();
    float tot = red[0] + red[1] + red[2] + red[3];
    float rs = rsqrtf(tot / (float)HID + 1e-5f);
    for (int c = tid; c < HID / 4; c += 256) {
      float4 v = xr[c];
      float4 s4 = sc[c];
      ushort4 o;
      o.x = f2bf(v.x * rs * s4.x); o.y = f2bf(v.y * rs * s4.y);
      o.z = f2bf(v.z * rs * s4.z); o.w = f2bf(v.w * rs * s4.w);
      *(ushort4*)&t[(size_t)bid * HID + c * 4] = o;
    }
  } else if (bid < 8528) {
    const float* src; unsigned short* dst; long base0;
    if (bid < 5648) { src = w1; dst = w1bf; base0 = (long)(bid - 2048) * 1024; }
    else            { src = w2; dst = w2bf; base0 = (long)(bid - 5648) * 1024; }
    #pragma unroll
    for (int k2 = 0; k2 < 4; ++k2) {
      long base = (base0 + k2 * 256 + tid) * 4;
      float4 v = *(const float4*)&src[base];
      ushort4 o;
      o.x = f2bf(v.x); o.y = f2bf(v.y); o.z = f2bf(v.z); o.w = f2bf(v.w);
      *(ushort4*)&dst[base] = o;
    }
  } else {
    int idx = (bid - 8528) * 256 + tid;     // < 65536
    int pos = idx >> 5, i = idx & 31;
    const double theta = 150000.0;
    const double two_pi = 6.283185307179586476925286766559;
    double freq = pow(theta, (double)i / 32.0);
    double interp = 1.0 / (32.0 * freq);
    double extrap = 1.0 / freq;
    double low  = 32.0 * log(4096.0 / (32.0 * two_pi)) / log(theta);
    double high = 32.0 * log(4096.0 / (1.0  * two_pi)) / log(theta);
    double ramp = ((double)i - low) / (high - low);
    ramp = ramp < 0.0 ? 0.0 : (ramp > 1.0 ? 1.0 : ramp);
    double maskv = 1.0 - ramp;
    double inv = interp * (1.0 - maskv) + extrap * maskv;
    double ang = (double)pos * inv;
    double conc = 0.1 * log(32.0) + 1.0;
    ctab[idx] = (float)(cos(ang) * conc);
    stab[idx] = (float)(sin(ang) * conc);
  }
}

// ---------------- Pipelined GEMM, 2 blocks/CU, one barrier per K-tile ----
template<int BN, bool RESID>
__global__ __launch_bounds__(256, 2) void gemm_kernel(
    const unsigned short* __restrict__ A, const unsigned short* __restrict__ B,
    const float* __restrict__ bias, const float* __restrict__ resid,
    void* __restrict__ Cout, int K, int NC) {
  constexpr int NF = BN / 32;
  __shared__ unsigned short sA[2][8192];
  __shared__ unsigned short sB[2][BN * 64];

  const int tid = threadIdx.x;
  const int q8 = gridDim.x >> 3;
  const int sw = ((int)blockIdx.x & 7) * q8 + ((int)blockIdx.x >> 3);
  const int m0 = (sw & 15) * 128;
  const int n0 = (sw >> 4) * BN;

  const int lane = tid & 63, wid = tid >> 6;
  const int fr = lane & 15, fq = lane >> 4;
  const int wr = wid >> 1, wc = wid & 1;
  const int swz = (fr & 7) << 4;
  const int r_st = tid >> 3;
  const int c8_st = ((tid & 7) ^ ((tid >> 3) & 7)) * 8;
  const int wlds = wid << 9;

  const unsigned short* Ag = A + (size_t)(m0 + r_st) * K + c8_st;
  const unsigned short* Bg = B + (size_t)(n0 + r_st) * K + c8_st;

  f32x4 acc[4][NF] = {};
  const int NT = K >> 6;

  auto LDA_ = [&](int bs, int mf, int ks) -> short8 {
    int row = wr * 64 + mf * 16 + fr;
    int cb = (ks * 64 + fq * 16) ^ swz;
    return *(const short8*)((const char*)&sA[bs][0] + row * 128 + cb);
  };
  auto LDB_ = [&](int bs, int nf, int ks) -> short8 {
    int row = wc * (NF * 16) + nf * 16 + fr;
    int cb = (ks * 64 + fq * 16) ^ swz;
    return *(const short8*)((const char*)&sB[bs][0] + row * 128 + cb);
  };
  auto issue_tile = [&](int tt, int b) {
    const unsigned short* Agt = Ag + (size_t)tt * 64;
    const unsigned short* Bgt = Bg + (size_t)tt * 64;
    #pragma unroll
    for (int s = 0; s < 4; ++s)
      gload_lds16(Agt + (size_t)(s * 32) * K, &sA[b][s * 2048 + wlds]);
    #pragma unroll
    for (int s = 0; s < NF; ++s)
      gload_lds16(Bgt + (size_t)(s * 32) * K, &sB[b][s * 2048 + wlds]);
  };

  issue_tile(0, 0);

  for (int t = 0; t < NT; ++t) {
    const int cu = t & 1;
    asm volatile("s_waitcnt vmcnt(0)" ::: "memory");
    __builtin_amdgcn_s_barrier();
    __builtin_amdgcn_sched_barrier(0);
    if (t + 1 < NT) issue_tile(t + 1, cu ^ 1);
    short8 afr0[4], bfr0[NF], afr1[4], bfr1[NF];
    #pragma unroll
    for (int mf = 0; mf < 4; ++mf) afr0[mf] = LDA_(cu, mf, 0);
    #pragma unroll
    for (int nf = 0; nf < NF; ++nf) bfr0[nf] = LDB_(cu, nf, 0);
    #pragma unroll
    for (int mf = 0; mf < 4; ++mf) afr1[mf] = LDA_(cu, mf, 1);
    #pragma unroll
    for (int nf = 0; nf < NF; ++nf) bfr1[nf] = LDB_(cu, nf, 1);
    __builtin_amdgcn_s_setprio(1);
    #pragma unroll
    for (int mf = 0; mf < 4; ++mf)
      #pragma unroll
      for (int nf = 0; nf < NF; ++nf)
        acc[mf][nf] = MFMA16(afr0[mf], bfr0[nf], acc[mf][nf]);
    #pragma unroll
    for (int mf = 0; mf < 4; ++mf)
      #pragma unroll
      for (int nf = 0; nf < NF; ++nf)
        acc[mf][nf] = MFMA16(afr1[mf], bfr1[nf], acc[mf][nf]);
    __builtin_amdgcn_s_setprio(0);
  }

  if (!RESID) {
    unsigned short* C = (unsigned short*)Cout;
    #pragma unroll
    for (int mf = 0; mf < 4; ++mf)
      #pragma unroll
      for (int nf = 0; nf < NF; ++nf)
        #pragma unroll
        for (int r = 0; r < 4; ++r) {
          int row = m0 + wr * 64 + mf * 16 + fq * 4 + r;
          int col = n0 + wc * (NF * 16) + nf * 16 + fr;
          C[(size_t)row * NC + col] = f2bf(acc[mf][nf][r] + bias[col]);
        }
  } else {
    float* C = (float*)Cout;
    #pragma unroll
    for (int mf = 0; mf < 4; ++mf)
      #pragma unroll
      for (int nf = 0; nf < NF; ++nf)
        #pragma unroll
        for (int r = 0; r < 4; ++r) {
          int row = m0 + wr * 64 + mf * 16 + fq * 4 + r;
          int col = n0 + wc * (NF * 16) + nf * 16 + fr;
          C[(size_t)row * NC + col] = acc[mf][nf][r] + bias[col] + resid[(size_t)row * NC + col];
        }
  }
}

// ---------------- GQA attention: K/V staged ONCE per kv-head ----------------
__global__ __launch_bounds__(512) void attn_kernel(
    const unsigned short* __restrict__ qkv, const float* __restrict__ sinks,
    const float* __restrict__ ctab, const float* __restrict__ stab,
    unsigned short* __restrict__ attn) {
  const int tile = blockIdx.x;
  const int h = blockIdx.y;              // kv-head
  const int q0 = tile * 64;
  const int kbase = q0 - 127;

  __shared__ unsigned short Qsh[64][72];
  __shared__ unsigned short Ksh[192][72];
  __shared__ unsigned short Vt[64][200];   // transposed V: [dim][key]
  __shared__ unsigned short Wsh[64][200];  // P (separate: K lives all 8 iters)
  __shared__ float rowpart[4][64];
  __shared__ float invsum[64];

  const int tid = threadIdx.x;

  // ---- stage K with RoPE (192 rows x 4 chunk-pairs = 768 units)
  #pragma unroll
  for (int it = 0; it < 2; ++it) {
    int lin = tid + it * 512;
    if (lin < 768) {
      int r = lin >> 2, cp = lin & 3;
      int j = kbase + r;
      short8 oa = {}, ob = {};
      if (j >= 0 && j < NTOK) {
        const unsigned short* kp = &qkv[(size_t)j * QKVD + KOFF + h * 64 + cp * 8];
        short8 xa = *(const short8*)kp;
        short8 xb = *(const short8*)(kp + 32);
        #pragma unroll
        for (int e = 0; e < 8; ++e) {
          float c = ctab[j * 32 + cp * 8 + e], s = stab[j * 32 + cp * 8 + e];
          float x1 = bf2f((unsigned short)xa[e]), x2 = bf2f((unsigned short)xb[e]);
          oa[e] = (short)f2bf(x1 * c - x2 * s);
          ob[e] = (short)f2bf(x2 * c + x1 * s);
        }
      }
      *(short8*)&Ksh[r][cp * 8] = oa;
      *(short8*)&Ksh[r][cp * 8 + 32] = ob;
    }
  }
  // ---- stage V transposed: coalesced column loads, conflict-free b128 writes
  {
    const int d = tid & 63;
    const int jg0 = tid >> 6;              // 0..7
    const unsigned short* vcol = qkv + VOFF + (size_t)h * 64 + d;
    #pragma unroll
    for (int it = 0; it < 3; ++it) {
      int jg = jg0 + it * 8;               // 0..23
      int jb = kbase + jg * 8;
      unsigned int e01 = 0, e23 = 0, e45 = 0, e67 = 0;
      if (jb >= 0) {
        e01 = (unsigned int)vcol[(size_t)(jb + 0) * QKVD]
            | ((unsigned int)vcol[(size_t)(jb + 1) * QKVD] << 16);
        e23 = (unsigned int)vcol[(size_t)(jb + 2) * QKVD]
            | ((unsigned int)vcol[(size_t)(jb + 3) * QKVD] << 16);
        e45 = (unsigned int)vcol[(size_t)(jb + 4) * QKVD]
            | ((unsigned int)vcol[(size_t)(jb + 5) * QKVD] << 16);
        e67 = (unsigned int)vcol[(size_t)(jb + 6) * QKVD]
            | ((unsigned int)vcol[(size_t)(jb + 7) * QKVD] << 16);
      } else if (jb + 7 >= 0) {
        unsigned short ev[8];
        #pragma unroll
        for (int e = 0; e < 8; ++e)
          ev[e] = (jb + e >= 0) ? vcol[(size_t)(jb + e) * QKVD] : (unsigned short)0;
        e01 = ev[0] | ((unsigned int)ev[1] << 16);
        e23 = ev[2] | ((unsigned int)ev[3] << 16);
        e45 = ev[4] | ((unsigned int)ev[5] << 16);
        e67 = ev[6] | ((unsigned int)ev[7] << 16);
      }
      *(uint4*)&Vt[d][jg * 8] = make_uint4(e01, e23, e45, e67);
    }
  }

  const int lane = tid & 63;
  const int wid = tid >> 6;                // 0..7
  const int fr = lane & 15;
  const int fq = lane >> 4;
  const int fc = fq * 8;
  const int rg = wid >> 2;                 // row group (0..1)
  const int cg = wid & 3;                  // key/col group (0..3)
  const int wk0 = cg * 48;

  for (int qm = 0; qm < 8; ++qm) {
    const int gh = h * 8 + qm;
    if (tid < 256) {
      int r = tid >> 2, cp = tid & 3;
      int i = q0 + r;
      const unsigned short* qp = &qkv[(size_t)i * QKVD + gh * 64 + cp * 8];
      short8 xa = *(const short8*)qp;
      short8 xb = *(const short8*)(qp + 32);
      short8 oa, ob;
      #pragma unroll
      for (int e = 0; e < 8; ++e) {
        float c = ctab[i * 32 + cp * 8 + e], s = stab[i * 32 + cp * 8 + e];
        float x1 = bf2f((unsigned short)xa[e]), x2 = bf2f((unsigned short)xb[e]);
        oa[e] = (short)f2bf(x1 * c - x2 * s);
        ob[e] = (short)f2bf(x2 * c + x1 * s);
      }
      *(short8*)&Qsh[r][cp * 8] = oa;
      *(short8*)&Qsh[r][cp * 8 + 32] = ob;
    }
    __syncthreads();   // Q (and, iter 0, K/V) staged

    f32x4 sc[2][3] = {};
    #pragma unroll
    for (int k0 = 0; k0 < 64; k0 += 32) {
      short8 qa[2], kb[3];
      #pragma unroll
      for (int mi = 0; mi < 2; ++mi)
        qa[mi] = *(const short8*)&Qsh[rg * 32 + mi * 16 + fr][k0 + fc];
      #pragma unroll
      for (int ni = 0; ni < 3; ++ni)
        kb[ni] = *(const short8*)&Ksh[wk0 + ni * 16 + fr][k0 + fc];
      #pragma unroll
      for (int mi = 0; mi < 2; ++mi)
        #pragma unroll
        for (int ni = 0; ni < 3; ++ni)
          sc[mi][ni] = MFMA16(qa[mi], kb[ni], sc[mi][ni]);
    }

    #pragma unroll
    for (int mi = 0; mi < 2; ++mi)
      #pragma unroll
      for (int r = 0; r < 4; ++r) {
        int row = rg * 32 + mi * 16 + fq * 4 + r;
        int i = q0 + row;
        float rs = 0.f;
        #pragma unroll
        for (int ni = 0; ni < 3; ++ni) {
          int kk = wk0 + ni * 16 + fr;
          int j = kbase + kk;
          bool valid = (j >= 0) && (j <= i) && (j > i - 128);
          float pw = valid ? __expf(sc[mi][ni][r] * 0.125f) : 0.f;
          sc[mi][ni][r] = pw;
          rs += pw;
        }
        rs += __shfl_xor(rs, 1);
        rs += __shfl_xor(rs, 2);
        rs += __shfl_xor(rs, 4);
        rs += __shfl_xor(rs, 8);
        #pragma unroll
        for (int ni = 0; ni < 3; ++ni)
          Wsh[row][wk0 + ni * 16 + fr] = f2bf(sc[mi][ni][r]);
        if (fr == 0) rowpart[cg][row] = rs;
      }
    __syncthreads();   // P + partials visible

    if (tid < 64) {
      float tot = rowpart[0][tid] + rowpart[1][tid] + rowpart[2][tid] + rowpart[3][tid];
      invsum[tid] = 1.f / (tot + __expf(sinks[gh]));
    }

    f32x4 pv[2] = {};
    #pragma unroll
    for (int k0 = 0; k0 < 192; k0 += 32) {
      short8 pa[2];
      #pragma unroll
      for (int mi = 0; mi < 2; ++mi)
        pa[mi] = *(const short8*)&Wsh[rg * 32 + mi * 16 + fr][k0 + fc];
      short8 vb = *(const short8*)&Vt[cg * 16 + fr][k0 + fc];
      #pragma unroll
      for (int mi = 0; mi < 2; ++mi)
        pv[mi] = MFMA16(pa[mi], vb, pv[mi]);
    }
    __syncthreads();   // invsum visible; Wsh reads complete

    #pragma unroll
    for (int mi = 0; mi < 2; ++mi)
      #pragma unroll
      for (int r = 0; r < 4; ++r) {
        int row = rg * 32 + mi * 16 + fq * 4 + r;
        float inv = invsum[row];
        int col = cg * 16 + fr;
        attn[(size_t)(q0 + row) * ATTD + gh * 64 + col] = f2bf(pv[mi][r] * inv);
      }
  }
}

extern "C" void kernel_launch(void* const* d_in, const int* in_sizes, int n_in,
                              void* d_out, int out_size, void* d_ws, size_t ws_size,
                              hipStream_t stream) {
  const float* x          = (const float*)d_in[0];
  const float* norm_scale = (const float*)d_in[1];
  const float* sinks      = (const float*)d_in[2];
  const float* w_qkv      = (const float*)d_in[3];
  const float* b_qkv      = (const float*)d_in[4];
  const float* w_out      = (const float*)d_in[5];
  const float* b_out      = (const float*)d_in[6];
  float* out = (float*)d_out;

  char* ws = (char*)d_ws;
  unsigned short* qkv_bf = (unsigned short*)(ws);
  unsigned short* t_bf   = (unsigned short*)(ws + 20971520);
  unsigned short* attn_b = (unsigned short*)(ws + 20971520);
  unsigned short* w1bf   = (unsigned short*)(ws + 20971520 + 16777216);
  unsigned short* w2bf   = (unsigned short*)(ws + 20971520 + 16777216 + 29491200);
  float* ctab = (float*)(ws + 20971520 + 16777216 + 29491200 + 23592960);
  float* stab = ctab + NTOK * 32;

  // prep: rmsnorm (2048) || w_qkv cvt (3600) || w_out cvt (2880) || rope (256)
  prep_kernel<<<dim3(8784), dim3(256), 0, stream>>>(
      x, norm_scale, t_bf, w_qkv, w1bf, w_out, w2bf, ctab, stab);
  // GEMM1: 2048x5120x2880, tiles 128x160 -> 512 blocks (2/CU)
  gemm_kernel<160, false><<<dim3(512), dim3(256), 0, stream>>>(
      t_bf, w1bf, b_qkv, nullptr, (void*)qkv_bf, HID, QKVD);
  // attention: (32 tiles, 8 kv-heads), K/V staged once per block
  attn_kernel<<<dim3(32, 8), dim3(512), 0, stream>>>(qkv_bf, sinks, ctab, stab, attn_b);
  // GEMM2: 2048x2880x4096, tiles 128x96 -> 480 blocks (2/CU)
  gemm_kernel<96, true><<<dim3(480), dim3(256), 0, stream>>>(
      attn_b, w2bf, b_out, x, (void*)out, ATTD, HID);
}